// Round 3
// baseline (638.555 us; speedup 1.0000x reference)
//
#include <hip/hip_runtime.h>
#include <stdint.h>

#define N_TOK 4096
#define DIM   256
#define NH    4
#define DH    64
#define TOPK  30
#define CANDN 40      // candidate margin: approx-top-40 superset of exact top-30
#define ATT_SCALE 0.25f
#define LN_EPS 1e-5f

typedef __attribute__((ext_vector_type(8))) short bf16x8;  // 8 bf16 in 4 VGPRs
typedef __attribute__((ext_vector_type(4))) float f32x4;

static __device__ __forceinline__ ushort f2bf(float f) {   // RNE
    uint x = __float_as_uint(f);
    return (ushort)((x + 0x7FFFu + ((x >> 16) & 1u)) >> 16);
}
static __device__ __forceinline__ bf16x8 load_frag(const ushort* p) {
    union { int4 i; bf16x8 f; } u;
    u.i = *reinterpret_cast<const int4*>(p);
    return u.f;
}
static __device__ __forceinline__ uint s16key(uint u) {    // bf16 bits -> sortable u16
    return (u & 0x8000u) ? (u ^ 0xFFFFu) : (u | 0x8000u);
}

// ---------------------------------------------------------------------------
// fp32 GEMM NT: C[i][j] = sum_d A[i][d]*W[j][d] + bias[j] (+ addX[i][j]).
// M=4096, N=256, K=256. Vector-ALU (no fp32 MFMA on CDNA4). Block: 256 thr,
// tile 64x64, each thread 4x4 outputs. Optional bf16 mirror output.
// ---------------------------------------------------------------------------
#define BK 32
__global__ __launch_bounds__(256) void proj_gemm_f32(
    const float* __restrict__ A, const float* __restrict__ W,
    const float* __restrict__ bias, const float* __restrict__ addX,
    float* __restrict__ outF, ushort* __restrict__ outB)
{
    __shared__ float As[BK][64 + 4];   // [k][i], +4 pad keeps 16B alignment
    __shared__ float Ws[BK][64 + 4];   // [k][j]
    const int tid = threadIdx.x;
    const int tx = tid & 15;           // col group (4 cols)
    const int ty = tid >> 4;           // row group (4 rows)
    const int i0 = blockIdx.y * 64;
    const int j0 = blockIdx.x * 64;

    float acc[4][4];
#pragma unroll
    for (int r = 0; r < 4; r++)
#pragma unroll
        for (int c = 0; c < 4; c++) acc[r][c] = 0.f;

    for (int k0 = 0; k0 < DIM; k0 += BK) {
#pragma unroll
        for (int u = 0; u < 2; u++) {
            const int f = u * 256 + tid;          // 0..511
            const int r = f >> 3;                 // row 0..63
            const int c = (f & 7) * 4;            // k offset 0,4..28
            float4 va = *reinterpret_cast<const float4*>(A + (size_t)(i0 + r) * DIM + k0 + c);
            As[c + 0][r] = va.x; As[c + 1][r] = va.y;
            As[c + 2][r] = va.z; As[c + 3][r] = va.w;
            float4 vw = *reinterpret_cast<const float4*>(W + (size_t)(j0 + r) * DIM + k0 + c);
            Ws[c + 0][r] = vw.x; Ws[c + 1][r] = vw.y;
            Ws[c + 2][r] = vw.z; Ws[c + 3][r] = vw.w;
        }
        __syncthreads();
#pragma unroll
        for (int kk = 0; kk < BK; kk++) {
            const float4 a4 = *reinterpret_cast<const float4*>(&As[kk][ty * 4]);
            const float4 b4 = *reinterpret_cast<const float4*>(&Ws[kk][tx * 4]);
            const float ar[4] = {a4.x, a4.y, a4.z, a4.w};
            const float br[4] = {b4.x, b4.y, b4.z, b4.w};
#pragma unroll
            for (int r = 0; r < 4; r++)
#pragma unroll
                for (int c = 0; c < 4; c++) acc[r][c] += ar[r] * br[c];
        }
        __syncthreads();
    }

#pragma unroll
    for (int r = 0; r < 4; r++) {
        const int gi = i0 + ty * 4 + r;
#pragma unroll
        for (int c = 0; c < 4; c++) {
            const int gj = j0 + tx * 4 + c;
            float v = acc[r][c] + bias[gj];
            if (addX) v += addX[(size_t)gi * DIM + gj];
            if (outF) outF[(size_t)gi * DIM + gj] = v;
            if (outB) outB[(size_t)gi * DIM + gj] = f2bf(v);
        }
    }
}

// ---------------------------------------------------------------------------
// Approx scores (bf16 q/k via MFMA, fp32 accum) stored as SORTABLE U16 KEYS
// into sb. Unscaled (scale>0 preserves ranking). wg 256 thr; BM=128 (wave 32
// rows), BN=128, K=64 (one head slice).
// ---------------------------------------------------------------------------
__global__ __launch_bounds__(256) void scores_kernel(
    const ushort* __restrict__ qb, const ushort* __restrict__ kb,
    ushort* __restrict__ sb)
{
    const int lane = threadIdx.x & 63;
    const int wv   = threadIdx.x >> 6;
    const int h    = blockIdx.z;
    const int i0   = blockIdx.y * 128 + wv * 32;
    const int j0   = blockIdx.x * 128;
    const int r = lane & 15, q = lane >> 4;
    const int koff = h * DH;

    f32x4 acc[2][8];
#pragma unroll
    for (int a = 0; a < 2; a++)
#pragma unroll
        for (int b = 0; b < 8; b++) acc[a][b] = (f32x4){0.f, 0.f, 0.f, 0.f};

#pragma unroll
    for (int ks = 0; ks < 2; ks++) {
        const int kk = koff + ks * 32 + q * 8;
        bf16x8 af[2], bfr[8];
#pragma unroll
        for (int mt = 0; mt < 2; mt++)
            af[mt] = load_frag(qb + (size_t)(i0 + mt * 16 + r) * DIM + kk);
#pragma unroll
        for (int jt = 0; jt < 8; jt++)
            bfr[jt] = load_frag(kb + (size_t)(j0 + jt * 16 + r) * DIM + kk);
#pragma unroll
        for (int mt = 0; mt < 2; mt++)
#pragma unroll
            for (int jt = 0; jt < 8; jt++)
                acc[mt][jt] = __builtin_amdgcn_mfma_f32_16x16x32_bf16(
                    af[mt], bfr[jt], acc[mt][jt], 0, 0, 0);
    }

#pragma unroll
    for (int mt = 0; mt < 2; mt++)
#pragma unroll
        for (int rg = 0; rg < 4; rg++) {
            const int gi = i0 + mt * 16 + q * 4 + rg;   // C: row=(lane>>4)*4+reg
            ushort* row = sb + ((size_t)(h * N_TOK + gi)) * N_TOK;
#pragma unroll
            for (int jt = 0; jt < 8; jt++)
                row[j0 + jt * 16 + r] = (ushort)s16key(f2bf(acc[mt][jt][rg]));
        }
}

// ---------------------------------------------------------------------------
// Selection v2. 4 rows per 256-thr block (one wave per row, private LDS
// slices). Per wave: load 64 u16 keys/lane packed, row max, 256-bin LDS
// histogram of ulp-distance (maxkey - key), prefix-scan to rank-40 bin edge,
// compact candidates, exact fp32 rescore, bitonic sort (score desc, idx asc),
// softmax -> compact (idx,prob) + sparse ctx. Wave-uniform binary-search
// fallback if top-40 span > 255 ulps (practically never).
// ---------------------------------------------------------------------------
__global__ __launch_bounds__(256) void select_kernel(
    const ushort* __restrict__ sb, const float* __restrict__ qf,
    const float* __restrict__ kf, const float* __restrict__ vf,
    float* __restrict__ pval, int* __restrict__ pidx,
    float* __restrict__ ctx)
{
    const int lane = threadIdx.x & 63;
    const int wv   = threadIdx.x >> 6;
    const int row  = blockIdx.x * 4 + wv;      // 0..16383
    const int h    = row >> 12;
    const int i    = row & (N_TOK - 1);
    const ushort* srow = sb + (size_t)row * N_TOK;

    __shared__ uint  hist[4][256];
    __shared__ uint  cand[4][64];
    __shared__ uint  ccnt[4];
    __shared__ float pw[4][TOPK];
    __shared__ int   jw[4][TOPK];
    __shared__ __align__(16) float qsh[4][DH];

    qsh[wv][lane] = qf[(size_t)i * DIM + h * DH + lane];
    if (lane == 0) ccnt[wv] = 0;
#pragma unroll
    for (int b = 0; b < 4; b++) hist[wv][lane * 4 + b] = 0u;

    // 32 packed words = 64 u16 keys per lane, coalesced int4 loads
    uint kw[32];
    const int4* srow4 = reinterpret_cast<const int4*>(srow);
#pragma unroll
    for (int t = 0; t < 8; t++) {
        int4 c = srow4[t * 64 + lane];
        kw[t * 4 + 0] = (uint)c.x; kw[t * 4 + 1] = (uint)c.y;
        kw[t * 4 + 2] = (uint)c.z; kw[t * 4 + 3] = (uint)c.w;
    }

    // row max key
    uint mx = 0;
#pragma unroll
    for (int w = 0; w < 32; w++) {
        uint lo16 = kw[w] & 0xFFFFu, hi16 = kw[w] >> 16;
        mx = max(mx, max(lo16, hi16));
    }
#pragma unroll
    for (int off = 32; off; off >>= 1)
        mx = max(mx, (uint)__shfl_xor((int)mx, off));

    __syncthreads();   // hist zeros visible / ordered before atomics

    // histogram of ulp distance from max
#pragma unroll
    for (int w = 0; w < 32; w++) {
        uint lo16 = kw[w] & 0xFFFFu, hi16 = kw[w] >> 16;
        atomicAdd(&hist[wv][min(mx - lo16, 255u)], 1u);
        atomicAdd(&hist[wv][min(mx - hi16, 255u)], 1u);
    }
    __syncthreads();

    // prefix-scan bins (lane l owns bins 4l..4l+3), find rank-CANDN bin edge
    const uint c0 = hist[wv][lane * 4 + 0];
    const uint c1 = hist[wv][lane * 4 + 1];
    const uint c2 = hist[wv][lane * 4 + 2];
    const uint c3 = hist[wv][lane * 4 + 3];
    const uint seg = c0 + c1 + c2 + c3;
    uint scan = seg;
#pragma unroll
    for (int d = 1; d < 64; d <<= 1) {
        uint y = (uint)__shfl_up((int)scan, d);
        if (lane >= d) scan += y;
    }
    const uint excl = scan - seg;
    const bool crossing = (excl < CANDN) && (scan >= CANDN);
    unsigned long long bal = __ballot(crossing);
    const int srcLane = __ffsll(bal) - 1;     // exists: total count = 4096
    int tloc = lane * 4;
    if (crossing) {
        uint cum = excl + c0;
        if (cum < CANDN) { tloc++; cum += c1;
            if (cum < CANDN) { tloc++; cum += c2;
                if (cum < CANDN) { tloc++; } } }
    }
    const int t = __shfl(tloc, srcLane);

    uint T;
    if (t < 255) {
        T = mx - (uint)t;
    } else {
        // fallback: exact 16-bit binary search (wave-uniform, ~never taken)
        uint lo = 0;
#pragma unroll
        for (int b = 15; b >= 0; b--) {
            uint trial = lo | (1u << b);
            int c = 0;
#pragma unroll
            for (int w = 0; w < 32; w++) {
                c += ((kw[w] & 0xFFFFu) >= trial) ? 1 : 0;
                c += ((kw[w] >> 16)     >= trial) ? 1 : 0;
            }
#pragma unroll
            for (int off = 32; off; off >>= 1) c += __shfl_xor(c, off);
            if (c >= CANDN) lo = trial;
        }
        T = lo;
    }

    // compact candidate indices (cap 64)
#pragma unroll
    for (int w = 0; w < 32; w++) {
        const uint lo16 = kw[w] & 0xFFFFu, hi16 = kw[w] >> 16;
        const int jbase = (w >> 2) * 512 + lane * 8 + (w & 3) * 2;
        if (lo16 >= T) {
            uint pos = atomicAdd(&ccnt[wv], 1u);
            if (pos < 64u) cand[wv][pos] = (uint)jbase;
        }
        if (hi16 >= T) {
            uint pos = atomicAdd(&ccnt[wv], 1u);
            if (pos < 64u) cand[wv][pos] = (uint)(jbase + 1);
        }
    }
    __syncthreads();
    const int m = (int)min(ccnt[wv], 64u);

    // exact fp32 rescore of candidate `lane`
    unsigned long long ukey = 0ull;
    if (lane < m) {
        const int j = (int)cand[wv][lane];
        const float4* kr = reinterpret_cast<const float4*>(kf + (size_t)j * DIM + h * DH);
        const float4* qr = reinterpret_cast<const float4*>(qsh[wv]);
        float s = 0.f;
#pragma unroll
        for (int d = 0; d < 16; d++) {
            float4 a = qr[d], bb = kr[d];
            s += a.x * bb.x; s += a.y * bb.y; s += a.z * bb.z; s += a.w * bb.w;
        }
        uint bits = __float_as_uint(s);
        uint s32 = (bits & 0x80000000u) ? ~bits : (bits | 0x80000000u);
        ukey = ((unsigned long long)s32 << 12) | (unsigned long long)(4095 - j);
    }

    // bitonic sort ascending (key: score, tie: smaller index wins)
#pragma unroll
    for (int k = 2; k <= 64; k <<= 1) {
#pragma unroll
        for (int jj = k >> 1; jj > 0; jj >>= 1) {
            unsigned long long o = __shfl_xor(ukey, jj);
            bool keepMax = ((lane & jj) != 0) ^ ((lane & k) != 0);
            ukey = keepMax ? (ukey > o ? ukey : o) : (ukey < o ? ukey : o);
        }
    }

    const int rank = 63 - lane;          // 0 = best
    const int jsel = 4095 - (int)(ukey & 0xFFFull);
    uint s32b = (uint)(ukey >> 12);
    uint fb = (s32b & 0x80000000u) ? (s32b ^ 0x80000000u) : ~s32b;
    const float sc = __uint_as_float(fb);
    const float stop = __shfl(sc, 63);   // max exact score (lane 63 real: m>=40)

    float e = (rank < TOPK) ? __expf((sc - stop) * ATT_SCALE) : 0.f;
    float esum = e;
#pragma unroll
    for (int off = 32; off; off >>= 1) esum += __shfl_xor(esum, off);
    const float p = e / esum;

    if (rank < TOPK) {
        pw[wv][rank] = p; jw[wv][rank] = jsel;
        pval[(size_t)row * 32 + rank] = p;
        pidx[(size_t)row * 32 + rank] = jsel;
    }
    __syncthreads();

    // sparse ctx: ctx[i][h*64+d] = sum_c p_c * v[j_c][h*64+d]
    float a = 0.f;
#pragma unroll
    for (int c = 0; c < TOPK; c++)
        a += pw[wv][c] * vf[(size_t)jw[wv][c] * DIM + h * DH + lane];
    ctx[(size_t)i * DIM + h * DH + lane] = a;
}

// ---------------------------------------------------------------------------
// Write final fp32 attn tensor: zero row + scatter 30 probs.
// ---------------------------------------------------------------------------
__global__ __launch_bounds__(256) void attn_write(
    const float* __restrict__ pval, const int* __restrict__ pidx,
    float* __restrict__ attnF)
{
    const int r = blockIdx.x;
    float* rowp = attnF + (size_t)r * N_TOK;
    float4* row4 = reinterpret_cast<float4*>(rowp);
    const float4 z = {0.f, 0.f, 0.f, 0.f};
#pragma unroll
    for (int t = 0; t < 4; t++) row4[t * 256 + threadIdx.x] = z;
    __syncthreads();   // zeros drained before scatter
    if (threadIdx.x < TOPK)
        rowp[pidx[(size_t)r * 32 + threadIdx.x]] = pval[(size_t)r * 32 + threadIdx.x];
}

// ---------------------------------------------------------------------------
// Row LayerNorm (biased var), in-place on fp32 resid. One wave per row.
// ---------------------------------------------------------------------------
__global__ __launch_bounds__(64) void ln_kernel(
    float* __restrict__ resb, const float* __restrict__ g,
    const float* __restrict__ b)
{
    const int i = blockIdx.x, lane = threadIdx.x;
    float4* rowp = reinterpret_cast<float4*>(resb + (size_t)i * DIM);
    float4 x = rowp[lane];
    float s  = x.x + x.y + x.z + x.w;
    float sq = x.x * x.x + x.y * x.y + x.z * x.z + x.w * x.w;
#pragma unroll
    for (int off = 32; off; off >>= 1) {
        s  += __shfl_xor(s, off);
        sq += __shfl_xor(sq, off);
    }
    const float mu  = s * (1.f / DIM);
    const float var = sq * (1.f / DIM) - mu * mu;
    const float rstd = rsqrtf(var + LN_EPS);
    const int col = lane * 4;
    float4 o;
    o.x = (x.x - mu) * rstd * g[col + 0] + b[col + 0];
    o.y = (x.y - mu) * rstd * g[col + 1] + b[col + 1];
    o.z = (x.z - mu) * rstd * g[col + 2] + b[col + 2];
    o.w = (x.w - mu) * rstd * g[col + 3] + b[col + 3];
    rowp[lane] = o;
}

// ---------------------------------------------------------------------------
extern "C" void kernel_launch(void* const* d_in, const int* in_sizes, int n_in,
                              void* d_out, int out_size, void* d_ws, size_t ws_size,
                              hipStream_t stream)
{
    const float* key_in   = (const float*)d_in[0];
    const float* value_in = (const float*)d_in[1];
    const float* query_in = (const float*)d_in[2];
    const float* Wq = (const float*)d_in[3];
    const float* bq = (const float*)d_in[4];
    const float* Wk = (const float*)d_in[5];
    const float* bk = (const float*)d_in[6];
    const float* Wv = (const float*)d_in[7];
    const float* bv = (const float*)d_in[8];
    const float* Wo = (const float*)d_in[9];
    const float* bo = (const float*)d_in[10];
    const float* ln_g = (const float*)d_in[11];
    const float* ln_b = (const float*)d_in[12];

    float* outF  = (float*)d_out;                     // (N, D) fp32, 1M floats
    float* attnF = outF + (size_t)N_TOK * DIM;        // (H, N, N) fp32, 67.1M floats

    // Large scratch carved inside the attn output region (consumed before
    // attn_write overwrites it).
    const size_t SC = 33554432;               // 2 ushorts per attn float slot
    ushort* sb  = (ushort*)attnF;             // u16 sortable keys (128 MB)
    float*  qf  = attnF + SC;
    float*  kf  = attnF + SC + 1048576;
    float*  vf  = attnF + SC + 2097152;
    ushort* qb  = (ushort*)(attnF + SC + 3145728);
    ushort* kb  = (ushort*)(attnF + SC + 3670016);
    float*  ctx = attnF + SC + 4194304;

    float* pval = (float*)d_ws;               // 16384 * 32 fp32 (2 MB)
    int*   pidx = (int*)d_ws + 524288;        // 16384 * 32 int  (2 MB)

    const dim3 gP(4, 64), bP(256);
    proj_gemm_f32<<<gP, bP, 0, stream>>>(query_in, Wq, bq, nullptr, qf, qb);
    proj_gemm_f32<<<gP, bP, 0, stream>>>(key_in,   Wk, bk, nullptr, kf, kb);
    proj_gemm_f32<<<gP, bP, 0, stream>>>(value_in, Wv, bv, nullptr, vf, nullptr);

    scores_kernel<<<dim3(32, 32, NH), 256, 0, stream>>>(qb, kb, sb);
    select_kernel<<<dim3(N_TOK * NH / 4), 256, 0, stream>>>(sb, qf, kf, vf, pval, pidx, ctx);

    proj_gemm_f32<<<gP, bP, 0, stream>>>(ctx, Wo, bo, query_in, outF, nullptr);
    ln_kernel<<<N_TOK, 64, 0, stream>>>(outF, ln_g, ln_b);

    attn_write<<<N_TOK * NH, 256, 0, stream>>>(pval, pidx, attnF);
}

// Round 4
// 475.659 us; speedup vs baseline: 1.3425x; 1.3425x over previous
//
#include <hip/hip_runtime.h>
#include <stdint.h>

#define N_TOK 4096
#define DIM   256
#define NH    4
#define DH    64
#define TOPK  30
#define CANDN 40      // candidate margin: approx-top-40 superset of exact top-30
#define ATT_SCALE 0.25f
#define LN_EPS 1e-5f

typedef __attribute__((ext_vector_type(8))) short bf16x8;  // 8 bf16 in 4 VGPRs
typedef __attribute__((ext_vector_type(4))) float f32x4;

static __device__ __forceinline__ ushort f2bf(float f) {   // RNE
    uint x = __float_as_uint(f);
    return (ushort)((x + 0x7FFFu + ((x >> 16) & 1u)) >> 16);
}
static __device__ __forceinline__ bf16x8 load_frag(const ushort* p) {
    union { int4 i; bf16x8 f; } u;
    u.i = *reinterpret_cast<const int4*>(p);
    return u.f;
}
static __device__ __forceinline__ uint s16key(uint u) {    // bf16 bits -> sortable u16
    return (u & 0x8000u) ? (u ^ 0xFFFFu) : (u | 0x8000u);
}

// ---------------------------------------------------------------------------
// fp32 GEMM NT: C[i][j] = sum_d A[i][d]*W[j][d] + bias[j] (+ addX[i][j]).
// M=4096, N=256, K=256. Vector-ALU (no fp32 MFMA on CDNA4). Block: 256 thr,
// tile 64x64, each thread 4x4 outputs. Optional bf16 mirror output.
// ---------------------------------------------------------------------------
#define BK 32
__global__ __launch_bounds__(256) void proj_gemm_f32(
    const float* __restrict__ A, const float* __restrict__ W,
    const float* __restrict__ bias, const float* __restrict__ addX,
    float* __restrict__ outF, ushort* __restrict__ outB)
{
    __shared__ float As[BK][64 + 4];   // [k][i], +4 pad keeps 16B alignment
    __shared__ float Ws[BK][64 + 4];   // [k][j]
    const int tid = threadIdx.x;
    const int tx = tid & 15;           // col group (4 cols)
    const int ty = tid >> 4;           // row group (4 rows)
    const int i0 = blockIdx.y * 64;
    const int j0 = blockIdx.x * 64;

    float acc[4][4];
#pragma unroll
    for (int r = 0; r < 4; r++)
#pragma unroll
        for (int c = 0; c < 4; c++) acc[r][c] = 0.f;

    for (int k0 = 0; k0 < DIM; k0 += BK) {
#pragma unroll
        for (int u = 0; u < 2; u++) {
            const int f = u * 256 + tid;          // 0..511
            const int r = f >> 3;                 // row 0..63
            const int c = (f & 7) * 4;            // k offset 0,4..28
            float4 va = *reinterpret_cast<const float4*>(A + (size_t)(i0 + r) * DIM + k0 + c);
            As[c + 0][r] = va.x; As[c + 1][r] = va.y;
            As[c + 2][r] = va.z; As[c + 3][r] = va.w;
            float4 vw = *reinterpret_cast<const float4*>(W + (size_t)(j0 + r) * DIM + k0 + c);
            Ws[c + 0][r] = vw.x; Ws[c + 1][r] = vw.y;
            Ws[c + 2][r] = vw.z; Ws[c + 3][r] = vw.w;
        }
        __syncthreads();
#pragma unroll
        for (int kk = 0; kk < BK; kk++) {
            const float4 a4 = *reinterpret_cast<const float4*>(&As[kk][ty * 4]);
            const float4 b4 = *reinterpret_cast<const float4*>(&Ws[kk][tx * 4]);
            const float ar[4] = {a4.x, a4.y, a4.z, a4.w};
            const float br[4] = {b4.x, b4.y, b4.z, b4.w};
#pragma unroll
            for (int r = 0; r < 4; r++)
#pragma unroll
                for (int c = 0; c < 4; c++) acc[r][c] += ar[r] * br[c];
        }
        __syncthreads();
    }

#pragma unroll
    for (int r = 0; r < 4; r++) {
        const int gi = i0 + ty * 4 + r;
#pragma unroll
        for (int c = 0; c < 4; c++) {
            const int gj = j0 + tx * 4 + c;
            float v = acc[r][c] + bias[gj];
            if (addX) v += addX[(size_t)gi * DIM + gj];
            if (outF) outF[(size_t)gi * DIM + gj] = v;
            if (outB) outB[(size_t)gi * DIM + gj] = f2bf(v);
        }
    }
}

// ---------------------------------------------------------------------------
// Approx scores (bf16 q/k via MFMA, fp32 accum) stored as SORTABLE U16 KEYS
// into sb. Unscaled (scale>0 preserves ranking). wg 256 thr; BM=128 (wave 32
// rows), BN=128, K=64 (one head slice).
// ---------------------------------------------------------------------------
__global__ __launch_bounds__(256) void scores_kernel(
    const ushort* __restrict__ qb, const ushort* __restrict__ kb,
    ushort* __restrict__ sb)
{
    const int lane = threadIdx.x & 63;
    const int wv   = threadIdx.x >> 6;
    const int h    = blockIdx.z;
    const int i0   = blockIdx.y * 128 + wv * 32;
    const int j0   = blockIdx.x * 128;
    const int r = lane & 15, q = lane >> 4;
    const int koff = h * DH;

    f32x4 acc[2][8];
#pragma unroll
    for (int a = 0; a < 2; a++)
#pragma unroll
        for (int b = 0; b < 8; b++) acc[a][b] = (f32x4){0.f, 0.f, 0.f, 0.f};

#pragma unroll
    for (int ks = 0; ks < 2; ks++) {
        const int kk = koff + ks * 32 + q * 8;
        bf16x8 af[2], bfr[8];
#pragma unroll
        for (int mt = 0; mt < 2; mt++)
            af[mt] = load_frag(qb + (size_t)(i0 + mt * 16 + r) * DIM + kk);
#pragma unroll
        for (int jt = 0; jt < 8; jt++)
            bfr[jt] = load_frag(kb + (size_t)(j0 + jt * 16 + r) * DIM + kk);
#pragma unroll
        for (int mt = 0; mt < 2; mt++)
#pragma unroll
            for (int jt = 0; jt < 8; jt++)
                acc[mt][jt] = __builtin_amdgcn_mfma_f32_16x16x32_bf16(
                    af[mt], bfr[jt], acc[mt][jt], 0, 0, 0);
    }

#pragma unroll
    for (int mt = 0; mt < 2; mt++)
#pragma unroll
        for (int rg = 0; rg < 4; rg++) {
            const int gi = i0 + mt * 16 + q * 4 + rg;   // C: row=(lane>>4)*4+reg
            ushort* row = sb + ((size_t)(h * N_TOK + gi)) * N_TOK;
#pragma unroll
            for (int jt = 0; jt < 8; jt++)
                row[j0 + jt * 16 + r] = (ushort)s16key(f2bf(acc[mt][jt][rg]));
        }
}

// ---------------------------------------------------------------------------
// Selection v3. 4 rows per 256-thr block (one wave per row, private LDS
// slices). Histogram only keys within 254 ulps of row max (the rest cannot
// be in the top-40; unfiltered version serialized on bin 255 -> 5.3e7 LDS
// conflict cycles in round 3). Prefix-scan to rank-40 bin edge; wave-uniform
// exact binary-search fallback if the window holds < CANDN keys.
// ---------------------------------------------------------------------------
__global__ __launch_bounds__(256) void select_kernel(
    const ushort* __restrict__ sb, const float* __restrict__ qf,
    const float* __restrict__ kf, const float* __restrict__ vf,
    float* __restrict__ pval, int* __restrict__ pidx,
    float* __restrict__ ctx)
{
    const int lane = threadIdx.x & 63;
    const int wv   = threadIdx.x >> 6;
    const int row  = blockIdx.x * 4 + wv;      // 0..16383
    const int h    = row >> 12;
    const int i    = row & (N_TOK - 1);
    const ushort* srow = sb + (size_t)row * N_TOK;

    __shared__ uint  hist[4][256];
    __shared__ uint  cand[4][64];
    __shared__ uint  ccnt[4];
    __shared__ float pw[4][TOPK];
    __shared__ int   jw[4][TOPK];
    __shared__ __align__(16) float qsh[4][DH];

    qsh[wv][lane] = qf[(size_t)i * DIM + h * DH + lane];
    if (lane == 0) ccnt[wv] = 0;
#pragma unroll
    for (int b = 0; b < 4; b++) hist[wv][b * 64 + lane] = 0u;  // stride-64: 2-way, free

    // 32 packed words = 64 u16 keys per lane, coalesced int4 loads
    uint kw[32];
    const int4* srow4 = reinterpret_cast<const int4*>(srow);
#pragma unroll
    for (int t = 0; t < 8; t++) {
        int4 c = srow4[t * 64 + lane];
        kw[t * 4 + 0] = (uint)c.x; kw[t * 4 + 1] = (uint)c.y;
        kw[t * 4 + 2] = (uint)c.z; kw[t * 4 + 3] = (uint)c.w;
    }

    // row max key
    uint mx = 0;
#pragma unroll
    for (int w = 0; w < 32; w++) {
        uint lo16 = kw[w] & 0xFFFFu, hi16 = kw[w] >> 16;
        mx = max(mx, max(lo16, hi16));
    }
#pragma unroll
    for (int off = 32; off; off >>= 1)
        mx = max(mx, (uint)__shfl_xor((int)mx, off));

    __syncthreads();   // hist zeros visible before atomics

    // histogram of ulp distance from max — ONLY keys inside the 254-ulp window
#pragma unroll
    for (int w = 0; w < 32; w++) {
        uint d0 = mx - (kw[w] & 0xFFFFu);
        uint d1 = mx - (kw[w] >> 16);
        if (d0 < 255u) atomicAdd(&hist[wv][d0], 1u);
        if (d1 < 255u) atomicAdd(&hist[wv][d1], 1u);
    }
    __syncthreads();

    // prefix-scan bins (lane l owns bins 4l..4l+3), find rank-CANDN bin edge
    const uint c0 = hist[wv][lane * 4 + 0];
    const uint c1 = hist[wv][lane * 4 + 1];
    const uint c2 = hist[wv][lane * 4 + 2];
    const uint c3 = hist[wv][lane * 4 + 3];
    const uint seg = c0 + c1 + c2 + c3;
    uint scan = seg;
#pragma unroll
    for (int d = 1; d < 64; d <<= 1) {
        uint y = (uint)__shfl_up((int)scan, d);
        if (lane >= d) scan += y;
    }
    const uint excl = scan - seg;
    const bool crossing = (excl < CANDN) && (scan >= CANDN);
    unsigned long long bal = __ballot(crossing);

    int t = 256;                               // sentinel -> fallback
    if (bal != 0ull) {
        const int srcLane = __ffsll(bal) - 1;
        int tloc = lane * 4;
        if (crossing) {
            uint cum = excl + c0;
            if (cum < CANDN) { tloc++; cum += c1;
                if (cum < CANDN) { tloc++; cum += c2;
                    if (cum < CANDN) { tloc++; } } }
        }
        t = __shfl(tloc, srcLane);
    }

    uint T;
    if (t <= 254) {
        T = mx - (uint)t;
    } else {
        // fallback: exact 16-bit binary search (wave-uniform, ~never taken)
        uint lo = 0;
#pragma unroll
        for (int b = 15; b >= 0; b--) {
            uint trial = lo | (1u << b);
            int c = 0;
#pragma unroll
            for (int w = 0; w < 32; w++) {
                c += ((kw[w] & 0xFFFFu) >= trial) ? 1 : 0;
                c += ((kw[w] >> 16)     >= trial) ? 1 : 0;
            }
#pragma unroll
            for (int off = 32; off; off >>= 1) c += __shfl_xor(c, off);
            if (c >= CANDN) lo = trial;
        }
        T = lo;
    }

    // compact candidate indices (cap 64)
#pragma unroll
    for (int w = 0; w < 32; w++) {
        const uint lo16 = kw[w] & 0xFFFFu, hi16 = kw[w] >> 16;
        const int jbase = (w >> 2) * 512 + lane * 8 + (w & 3) * 2;
        if (lo16 >= T) {
            uint pos = atomicAdd(&ccnt[wv], 1u);
            if (pos < 64u) cand[wv][pos] = (uint)jbase;
        }
        if (hi16 >= T) {
            uint pos = atomicAdd(&ccnt[wv], 1u);
            if (pos < 64u) cand[wv][pos] = (uint)(jbase + 1);
        }
    }
    __syncthreads();
    const int m = (int)min(ccnt[wv], 64u);

    // exact fp32 rescore of candidate `lane`
    unsigned long long ukey = 0ull;
    if (lane < m) {
        const int j = (int)cand[wv][lane];
        const float4* kr = reinterpret_cast<const float4*>(kf + (size_t)j * DIM + h * DH);
        const float4* qr = reinterpret_cast<const float4*>(qsh[wv]);
        float s = 0.f;
#pragma unroll
        for (int d = 0; d < 16; d++) {
            float4 a = qr[d], bb = kr[d];
            s += a.x * bb.x; s += a.y * bb.y; s += a.z * bb.z; s += a.w * bb.w;
        }
        uint bits = __float_as_uint(s);
        uint s32 = (bits & 0x80000000u) ? ~bits : (bits | 0x80000000u);
        ukey = ((unsigned long long)s32 << 12) | (unsigned long long)(4095 - j);
    }

    // bitonic sort ascending (key: score, tie: smaller index wins)
#pragma unroll
    for (int k = 2; k <= 64; k <<= 1) {
#pragma unroll
        for (int jj = k >> 1; jj > 0; jj >>= 1) {
            unsigned long long o = __shfl_xor(ukey, jj);
            bool keepMax = ((lane & jj) != 0) ^ ((lane & k) != 0);
            ukey = keepMax ? (ukey > o ? ukey : o) : (ukey < o ? ukey : o);
        }
    }

    const int rank = 63 - lane;          // 0 = best
    const int jsel = 4095 - (int)(ukey & 0xFFFull);
    uint s32b = (uint)(ukey >> 12);
    uint fb = (s32b & 0x80000000u) ? (s32b ^ 0x80000000u) : ~s32b;
    const float sc = __uint_as_float(fb);
    const float stop = __shfl(sc, 63);   // max exact score (lane 63 real: m>=40)

    float e = (rank < TOPK) ? __expf((sc - stop) * ATT_SCALE) : 0.f;
    float esum = e;
#pragma unroll
    for (int off = 32; off; off >>= 1) esum += __shfl_xor(esum, off);
    const float p = e / esum;

    if (rank < TOPK) {
        pw[wv][rank] = p; jw[wv][rank] = jsel;
        pval[(size_t)row * 32 + rank] = p;
        pidx[(size_t)row * 32 + rank] = jsel;
    }
    __syncthreads();

    // sparse ctx: ctx[i][h*64+d] = sum_c p_c * v[j_c][h*64+d]
    float a = 0.f;
#pragma unroll
    for (int c = 0; c < TOPK; c++)
        a += pw[wv][c] * vf[(size_t)jw[wv][c] * DIM + h * DH + lane];
    ctx[(size_t)i * DIM + h * DH + lane] = a;
}

// ---------------------------------------------------------------------------
// Write final fp32 attn tensor: zero row + scatter 30 probs.
// ---------------------------------------------------------------------------
__global__ __launch_bounds__(256) void attn_write(
    const float* __restrict__ pval, const int* __restrict__ pidx,
    float* __restrict__ attnF)
{
    const int r = blockIdx.x;
    float* rowp = attnF + (size_t)r * N_TOK;
    float4* row4 = reinterpret_cast<float4*>(rowp);
    const float4 z = {0.f, 0.f, 0.f, 0.f};
#pragma unroll
    for (int t = 0; t < 4; t++) row4[t * 256 + threadIdx.x] = z;
    __syncthreads();   // zeros drained before scatter
    if (threadIdx.x < TOPK)
        rowp[pidx[(size_t)r * 32 + threadIdx.x]] = pval[(size_t)r * 32 + threadIdx.x];
}

// ---------------------------------------------------------------------------
// Row LayerNorm (biased var), in-place on fp32 resid. One wave per row.
// ---------------------------------------------------------------------------
__global__ __launch_bounds__(64) void ln_kernel(
    float* __restrict__ resb, const float* __restrict__ g,
    const float* __restrict__ b)
{
    const int i = blockIdx.x, lane = threadIdx.x;
    float4* rowp = reinterpret_cast<float4*>(resb + (size_t)i * DIM);
    float4 x = rowp[lane];
    float s  = x.x + x.y + x.z + x.w;
    float sq = x.x * x.x + x.y * x.y + x.z * x.z + x.w * x.w;
#pragma unroll
    for (int off = 32; off; off >>= 1) {
        s  += __shfl_xor(s, off);
        sq += __shfl_xor(sq, off);
    }
    const float mu  = s * (1.f / DIM);
    const float var = sq * (1.f / DIM) - mu * mu;
    const float rstd = rsqrtf(var + LN_EPS);
    const int col = lane * 4;
    float4 o;
    o.x = (x.x - mu) * rstd * g[col + 0] + b[col + 0];
    o.y = (x.y - mu) * rstd * g[col + 1] + b[col + 1];
    o.z = (x.z - mu) * rstd * g[col + 2] + b[col + 2];
    o.w = (x.w - mu) * rstd * g[col + 3] + b[col + 3];
    rowp[lane] = o;
}

// ---------------------------------------------------------------------------
extern "C" void kernel_launch(void* const* d_in, const int* in_sizes, int n_in,
                              void* d_out, int out_size, void* d_ws, size_t ws_size,
                              hipStream_t stream)
{
    const float* key_in   = (const float*)d_in[0];
    const float* value_in = (const float*)d_in[1];
    const float* query_in = (const float*)d_in[2];
    const float* Wq = (const float*)d_in[3];
    const float* bq = (const float*)d_in[4];
    const float* Wk = (const float*)d_in[5];
    const float* bk = (const float*)d_in[6];
    const float* Wv = (const float*)d_in[7];
    const float* bv = (const float*)d_in[8];
    const float* Wo = (const float*)d_in[9];
    const float* bo = (const float*)d_in[10];
    const float* ln_g = (const float*)d_in[11];
    const float* ln_b = (const float*)d_in[12];

    float* outF  = (float*)d_out;                     // (N, D) fp32, 1M floats
    float* attnF = outF + (size_t)N_TOK * DIM;        // (H, N, N) fp32, 67.1M floats

    // Large scratch carved inside the attn output region (consumed before
    // attn_write overwrites it).
    const size_t SC = 33554432;               // 2 ushorts per attn float slot
    ushort* sb  = (ushort*)attnF;             // u16 sortable keys (128 MB)
    float*  qf  = attnF + SC;
    float*  kf  = attnF + SC + 1048576;
    float*  vf  = attnF + SC + 2097152;
    ushort* qb  = (ushort*)(attnF + SC + 3145728);
    ushort* kb  = (ushort*)(attnF + SC + 3670016);
    float*  ctx = attnF + SC + 4194304;

    float* pval = (float*)d_ws;               // 16384 * 32 fp32 (2 MB)
    int*   pidx = (int*)d_ws + 524288;        // 16384 * 32 int  (2 MB)

    const dim3 gP(4, 64), bP(256);
    proj_gemm_f32<<<gP, bP, 0, stream>>>(query_in, Wq, bq, nullptr, qf, qb);
    proj_gemm_f32<<<gP, bP, 0, stream>>>(key_in,   Wk, bk, nullptr, kf, kb);
    proj_gemm_f32<<<gP, bP, 0, stream>>>(value_in, Wv, bv, nullptr, vf, nullptr);

    scores_kernel<<<dim3(32, 32, NH), 256, 0, stream>>>(qb, kb, sb);
    select_kernel<<<dim3(N_TOK * NH / 4), 256, 0, stream>>>(sb, qf, kf, vf, pval, pidx, ctx);

    proj_gemm_f32<<<gP, bP, 0, stream>>>(ctx, Wo, bo, query_in, outF, nullptr);
    ln_kernel<<<N_TOK, 64, 0, stream>>>(outF, ln_g, ln_b);

    attn_write<<<N_TOK * NH, 256, 0, stream>>>(pval, pidx, attnF);
}

// Round 5
// 440.482 us; speedup vs baseline: 1.4497x; 1.0799x over previous
//
#include <hip/hip_runtime.h>
#include <stdint.h>

#define N_TOK 4096
#define DIM   256
#define NH    4
#define DH    64
#define TOPK  30
#define CANDN 40      // candidate margin: approx-top-40 superset of exact top-30
#define ATT_SCALE 0.25f
#define LN_EPS 1e-5f

typedef __attribute__((ext_vector_type(8))) short bf16x8;  // 8 bf16 in 4 VGPRs
typedef __attribute__((ext_vector_type(4))) float f32x4;

static __device__ __forceinline__ ushort f2bf(float f) {   // RNE
    uint x = __float_as_uint(f);
    return (ushort)((x + 0x7FFFu + ((x >> 16) & 1u)) >> 16);
}
static __device__ __forceinline__ bf16x8 load_frag(const ushort* p) {
    union { int4 i; bf16x8 f; } u;
    u.i = *reinterpret_cast<const int4*>(p);
    return u.f;
}
static __device__ __forceinline__ uint s16key(uint u) {    // bf16 bits -> sortable u16
    return (u & 0x8000u) ? (u ^ 0xFFFFu) : (u | 0x8000u);
}

// ---------------------------------------------------------------------------
// Fused q+k fp32 GEMM NT (exactness needed for rescoring): for sel in {q,k}:
// out[i][j] = sum_d A[i][d]*W[j][d] + bias[j]. N=512 logical (q cols 0..255,
// k cols 256..511) -> 512 WGs = 2 waves/SIMD (round-4 version had 256 WGs =
// 1 wave/SIMD: LDS latency fully exposed).
// ---------------------------------------------------------------------------
#define BK 32
__global__ __launch_bounds__(256) void qk_gemm_f32(
    const float* __restrict__ query_in, const float* __restrict__ key_in,
    const float* __restrict__ Wq, const float* __restrict__ bq,
    const float* __restrict__ Wk, const float* __restrict__ bk,
    float* __restrict__ qf, float* __restrict__ kf,
    ushort* __restrict__ qb, ushort* __restrict__ kb)
{
    const int j0g = blockIdx.x * 64;          // 0..511
    const int sel = j0g >> 8;                 // 0=q, 1=k
    const int j0  = j0g & 255;
    const float* A    = sel ? key_in : query_in;
    const float* W    = sel ? Wk : Wq;
    const float* bias = sel ? bk : bq;
    float*  outF = sel ? kf : qf;
    ushort* outB = sel ? kb : qb;

    __shared__ float As[BK][64 + 4];
    __shared__ float Ws[BK][64 + 4];
    const int tid = threadIdx.x;
    const int tx = tid & 15;
    const int ty = tid >> 4;
    const int i0 = blockIdx.y * 64;

    float acc[4][4];
#pragma unroll
    for (int r = 0; r < 4; r++)
#pragma unroll
        for (int c = 0; c < 4; c++) acc[r][c] = 0.f;

    for (int k0 = 0; k0 < DIM; k0 += BK) {
#pragma unroll
        for (int u = 0; u < 2; u++) {
            const int f = u * 256 + tid;
            const int r = f >> 3;
            const int c = (f & 7) * 4;
            float4 va = *reinterpret_cast<const float4*>(A + (size_t)(i0 + r) * DIM + k0 + c);
            As[c + 0][r] = va.x; As[c + 1][r] = va.y;
            As[c + 2][r] = va.z; As[c + 3][r] = va.w;
            float4 vw = *reinterpret_cast<const float4*>(W + (size_t)(j0 + r) * DIM + k0 + c);
            Ws[c + 0][r] = vw.x; Ws[c + 1][r] = vw.y;
            Ws[c + 2][r] = vw.z; Ws[c + 3][r] = vw.w;
        }
        __syncthreads();
#pragma unroll
        for (int kk = 0; kk < BK; kk++) {
            const float4 a4 = *reinterpret_cast<const float4*>(&As[kk][ty * 4]);
            const float4 b4 = *reinterpret_cast<const float4*>(&Ws[kk][tx * 4]);
            const float ar[4] = {a4.x, a4.y, a4.z, a4.w};
            const float br[4] = {b4.x, b4.y, b4.z, b4.w};
#pragma unroll
            for (int r = 0; r < 4; r++)
#pragma unroll
                for (int c = 0; c < 4; c++) acc[r][c] += ar[r] * br[c];
        }
        __syncthreads();
    }

#pragma unroll
    for (int r = 0; r < 4; r++) {
        const int gi = i0 + ty * 4 + r;
#pragma unroll
        for (int c = 0; c < 4; c++) {
            const int gj = j0 + tx * 4 + c;
            float v = acc[r][c] + bias[gj];
            outF[(size_t)gi * DIM + gj] = v;
            outB[(size_t)gi * DIM + gj] = f2bf(v);
        }
    }
}

// ---------------------------------------------------------------------------
// Cast fp32 -> bf16: value_in (1M), Wv (64K), Wo (64K), one linear kernel.
// ---------------------------------------------------------------------------
__global__ __launch_bounds__(256) void cast_kernel(
    const float* __restrict__ value_in, const float* __restrict__ Wv,
    const float* __restrict__ Wo, ushort* __restrict__ value_b,
    ushort* __restrict__ Wv_b, ushort* __restrict__ Wo_b)
{
    const int id4 = blockIdx.x * 256 + threadIdx.x;   // one float4 per thread
    const int NV = 1048576 / 4, NW = 65536 / 4;
    const float* src; ushort* dst; int off;
    if (id4 < NV)            { src = value_in; dst = value_b; off = id4; }
    else if (id4 < NV + NW)  { src = Wv; dst = Wv_b; off = id4 - NV; }
    else                     { src = Wo; dst = Wo_b; off = id4 - NV - NW; }
    float4 v = reinterpret_cast<const float4*>(src)[off];
    ushort4 o = {f2bf(v.x), f2bf(v.y), f2bf(v.z), f2bf(v.w)};
    reinterpret_cast<ushort4*>(dst)[off] = o;
}

// ---------------------------------------------------------------------------
// bf16 MFMA GEMM NT: out[i][j] = sum_d A[i][d]*B[j][d] + bias[j] (+addX).
// M=4096, N=256, K=256. Grid (4,64): wave = 16 rows x 64 cols. Used for the
// v-projection and the out-projection (precision suffices: error ~1e-3 vs
// 0.0925 threshold; q/k stay fp32 for rescore exactness).
// ---------------------------------------------------------------------------
__global__ __launch_bounds__(256) void mfma_gemm(
    const ushort* __restrict__ A, const ushort* __restrict__ B,
    const float* __restrict__ bias, const float* __restrict__ addX,
    float* __restrict__ outF)
{
    const int lane = threadIdx.x & 63;
    const int wv   = threadIdx.x >> 6;
    const int i0   = blockIdx.y * 64 + wv * 16;
    const int j0   = blockIdx.x * 64;
    const int r = lane & 15, q = lane >> 4;

    f32x4 acc[4];
#pragma unroll
    for (int b = 0; b < 4; b++) acc[b] = (f32x4){0.f, 0.f, 0.f, 0.f};

#pragma unroll
    for (int ks = 0; ks < 8; ks++) {
        const int kk = ks * 32 + q * 8;
        bf16x8 af = load_frag(A + (size_t)(i0 + r) * DIM + kk);
        bf16x8 bfr[4];
#pragma unroll
        for (int jt = 0; jt < 4; jt++)
            bfr[jt] = load_frag(B + (size_t)(j0 + jt * 16 + r) * DIM + kk);
#pragma unroll
        for (int jt = 0; jt < 4; jt++)
            acc[jt] = __builtin_amdgcn_mfma_f32_16x16x32_bf16(af, bfr[jt], acc[jt], 0, 0, 0);
    }

#pragma unroll
    for (int jt = 0; jt < 4; jt++) {
        const int gj = j0 + jt * 16 + r;          // col = lane&15
        const float bv = bias[gj];
#pragma unroll
        for (int rg = 0; rg < 4; rg++) {          // row = (lane>>4)*4+reg
            const int gi = i0 + q * 4 + rg;
            float v = acc[jt][rg] + bv;
            if (addX) v += addX[(size_t)gi * DIM + gj];
            outF[(size_t)gi * DIM + gj] = v;
        }
    }
}

// ---------------------------------------------------------------------------
// Approx scores (bf16 q/k via MFMA, fp32 accum) stored as SORTABLE U16 KEYS
// into sb. Unscaled (scale>0 preserves ranking). wg 256 thr; BM=128 (wave 32
// rows), BN=128, K=64 (one head slice).
// ---------------------------------------------------------------------------
__global__ __launch_bounds__(256) void scores_kernel(
    const ushort* __restrict__ qb, const ushort* __restrict__ kb,
    ushort* __restrict__ sb)
{
    const int lane = threadIdx.x & 63;
    const int wv   = threadIdx.x >> 6;
    const int h    = blockIdx.z;
    const int i0   = blockIdx.y * 128 + wv * 32;
    const int j0   = blockIdx.x * 128;
    const int r = lane & 15, q = lane >> 4;
    const int koff = h * DH;

    f32x4 acc[2][8];
#pragma unroll
    for (int a = 0; a < 2; a++)
#pragma unroll
        for (int b = 0; b < 8; b++) acc[a][b] = (f32x4){0.f, 0.f, 0.f, 0.f};

#pragma unroll
    for (int ks = 0; ks < 2; ks++) {
        const int kk = koff + ks * 32 + q * 8;
        bf16x8 af[2], bfr[8];
#pragma unroll
        for (int mt = 0; mt < 2; mt++)
            af[mt] = load_frag(qb + (size_t)(i0 + mt * 16 + r) * DIM + kk);
#pragma unroll
        for (int jt = 0; jt < 8; jt++)
            bfr[jt] = load_frag(kb + (size_t)(j0 + jt * 16 + r) * DIM + kk);
#pragma unroll
        for (int mt = 0; mt < 2; mt++)
#pragma unroll
            for (int jt = 0; jt < 8; jt++)
                acc[mt][jt] = __builtin_amdgcn_mfma_f32_16x16x32_bf16(
                    af[mt], bfr[jt], acc[mt][jt], 0, 0, 0);
    }

#pragma unroll
    for (int mt = 0; mt < 2; mt++)
#pragma unroll
        for (int rg = 0; rg < 4; rg++) {
            const int gi = i0 + mt * 16 + q * 4 + rg;   // C: row=(lane>>4)*4+reg
            ushort* row = sb + ((size_t)(h * N_TOK + gi)) * N_TOK;
#pragma unroll
            for (int jt = 0; jt < 8; jt++)
                row[j0 + jt * 16 + r] = (ushort)s16key(f2bf(acc[mt][jt][rg]));
        }
}

// ---------------------------------------------------------------------------
// Selection v3 (unchanged from round 4). 4 rows per 256-thr block. Histogram
// only keys within 254 ulps of row max; prefix-scan to rank-40 bin edge;
// exact fp32 rescore; bitonic sort; softmax; emits (idx,prob) + bf16 ctx.
// ---------------------------------------------------------------------------
__global__ __launch_bounds__(256) void select_kernel(
    const ushort* __restrict__ sb, const float* __restrict__ qf,
    const float* __restrict__ kf, const float* __restrict__ vf,
    float* __restrict__ pval, int* __restrict__ pidx,
    ushort* __restrict__ ctxb)
{
    const int lane = threadIdx.x & 63;
    const int wv   = threadIdx.x >> 6;
    const int row  = blockIdx.x * 4 + wv;      // 0..16383
    const int h    = row >> 12;
    const int i    = row & (N_TOK - 1);
    const ushort* srow = sb + (size_t)row * N_TOK;

    __shared__ uint  hist[4][256];
    __shared__ uint  cand[4][64];
    __shared__ uint  ccnt[4];
    __shared__ float pw[4][TOPK];
    __shared__ int   jw[4][TOPK];
    __shared__ __align__(16) float qsh[4][DH];

    qsh[wv][lane] = qf[(size_t)i * DIM + h * DH + lane];
    if (lane == 0) ccnt[wv] = 0;
#pragma unroll
    for (int b = 0; b < 4; b++) hist[wv][b * 64 + lane] = 0u;  // stride-64: free

    uint kw[32];
    const int4* srow4 = reinterpret_cast<const int4*>(srow);
#pragma unroll
    for (int t = 0; t < 8; t++) {
        int4 c = srow4[t * 64 + lane];
        kw[t * 4 + 0] = (uint)c.x; kw[t * 4 + 1] = (uint)c.y;
        kw[t * 4 + 2] = (uint)c.z; kw[t * 4 + 3] = (uint)c.w;
    }

    uint mx = 0;
#pragma unroll
    for (int w = 0; w < 32; w++) {
        uint lo16 = kw[w] & 0xFFFFu, hi16 = kw[w] >> 16;
        mx = max(mx, max(lo16, hi16));
    }
#pragma unroll
    for (int off = 32; off; off >>= 1)
        mx = max(mx, (uint)__shfl_xor((int)mx, off));

    __syncthreads();

#pragma unroll
    for (int w = 0; w < 32; w++) {
        uint d0 = mx - (kw[w] & 0xFFFFu);
        uint d1 = mx - (kw[w] >> 16);
        if (d0 < 255u) atomicAdd(&hist[wv][d0], 1u);
        if (d1 < 255u) atomicAdd(&hist[wv][d1], 1u);
    }
    __syncthreads();

    const uint c0 = hist[wv][lane * 4 + 0];
    const uint c1 = hist[wv][lane * 4 + 1];
    const uint c2 = hist[wv][lane * 4 + 2];
    const uint c3 = hist[wv][lane * 4 + 3];
    const uint seg = c0 + c1 + c2 + c3;
    uint scan = seg;
#pragma unroll
    for (int d = 1; d < 64; d <<= 1) {
        uint y = (uint)__shfl_up((int)scan, d);
        if (lane >= d) scan += y;
    }
    const uint excl = scan - seg;
    const bool crossing = (excl < CANDN) && (scan >= CANDN);
    unsigned long long bal = __ballot(crossing);

    int t = 256;
    if (bal != 0ull) {
        const int srcLane = __ffsll(bal) - 1;
        int tloc = lane * 4;
        if (crossing) {
            uint cum = excl + c0;
            if (cum < CANDN) { tloc++; cum += c1;
                if (cum < CANDN) { tloc++; cum += c2;
                    if (cum < CANDN) { tloc++; } } }
        }
        t = __shfl(tloc, srcLane);
    }

    uint T;
    if (t <= 254) {
        T = mx - (uint)t;
    } else {
        uint lo = 0;
#pragma unroll
        for (int b = 15; b >= 0; b--) {
            uint trial = lo | (1u << b);
            int c = 0;
#pragma unroll
            for (int w = 0; w < 32; w++) {
                c += ((kw[w] & 0xFFFFu) >= trial) ? 1 : 0;
                c += ((kw[w] >> 16)     >= trial) ? 1 : 0;
            }
#pragma unroll
            for (int off = 32; off; off >>= 1) c += __shfl_xor(c, off);
            if (c >= CANDN) lo = trial;
        }
        T = lo;
    }

#pragma unroll
    for (int w = 0; w < 32; w++) {
        const uint lo16 = kw[w] & 0xFFFFu, hi16 = kw[w] >> 16;
        const int jbase = (w >> 2) * 512 + lane * 8 + (w & 3) * 2;
        if (lo16 >= T) {
            uint pos = atomicAdd(&ccnt[wv], 1u);
            if (pos < 64u) cand[wv][pos] = (uint)jbase;
        }
        if (hi16 >= T) {
            uint pos = atomicAdd(&ccnt[wv], 1u);
            if (pos < 64u) cand[wv][pos] = (uint)(jbase + 1);
        }
    }
    __syncthreads();
    const int m = (int)min(ccnt[wv], 64u);

    unsigned long long ukey = 0ull;
    if (lane < m) {
        const int j = (int)cand[wv][lane];
        const float4* kr = reinterpret_cast<const float4*>(kf + (size_t)j * DIM + h * DH);
        const float4* qr = reinterpret_cast<const float4*>(qsh[wv]);
        float s = 0.f;
#pragma unroll
        for (int d = 0; d < 16; d++) {
            float4 a = qr[d], bb = kr[d];
            s += a.x * bb.x; s += a.y * bb.y; s += a.z * bb.z; s += a.w * bb.w;
        }
        uint bits = __float_as_uint(s);
        uint s32 = (bits & 0x80000000u) ? ~bits : (bits | 0x80000000u);
        ukey = ((unsigned long long)s32 << 12) | (unsigned long long)(4095 - j);
    }

#pragma unroll
    for (int k = 2; k <= 64; k <<= 1) {
#pragma unroll
        for (int jj = k >> 1; jj > 0; jj >>= 1) {
            unsigned long long o = __shfl_xor(ukey, jj);
            bool keepMax = ((lane & jj) != 0) ^ ((lane & k) != 0);
            ukey = keepMax ? (ukey > o ? ukey : o) : (ukey < o ? ukey : o);
        }
    }

    const int rank = 63 - lane;
    const int jsel = 4095 - (int)(ukey & 0xFFFull);
    uint s32b = (uint)(ukey >> 12);
    uint fb = (s32b & 0x80000000u) ? (s32b ^ 0x80000000u) : ~s32b;
    const float sc = __uint_as_float(fb);
    const float stop = __shfl(sc, 63);

    float e = (rank < TOPK) ? __expf((sc - stop) * ATT_SCALE) : 0.f;
    float esum = e;
#pragma unroll
    for (int off = 32; off; off >>= 1) esum += __shfl_xor(esum, off);
    const float p = e / esum;

    if (rank < TOPK) {
        pw[wv][rank] = p; jw[wv][rank] = jsel;
        pval[(size_t)row * 32 + rank] = p;
        pidx[(size_t)row * 32 + rank] = jsel;
    }
    __syncthreads();

    float a = 0.f;
#pragma unroll
    for (int c = 0; c < TOPK; c++)
        a += pw[wv][c] * vf[(size_t)jw[wv][c] * DIM + h * DH + lane];
    ctxb[(size_t)i * DIM + h * DH + lane] = f2bf(a);
}

// ---------------------------------------------------------------------------
// attn_write v2: 4 rows per block, LDS-staged (zero + scatter in LDS, one
// global write pass).
// ---------------------------------------------------------------------------
__global__ __launch_bounds__(256) void attn_write(
    const float* __restrict__ pval, const int* __restrict__ pidx,
    float* __restrict__ attnF)
{
    __shared__ __align__(16) float rb[4][N_TOK];
    const int tid = threadIdx.x;
    const int r0 = blockIdx.x * 4;

    float4* rb4 = reinterpret_cast<float4*>(&rb[0][0]);
    const float4 z = {0.f, 0.f, 0.f, 0.f};
#pragma unroll
    for (int t = 0; t < 16; t++) rb4[t * 256 + tid] = z;
    __syncthreads();
    if (tid < 4 * TOPK) {
        const int w = tid / TOPK, c = tid % TOPK;
        rb[w][pidx[(size_t)(r0 + w) * 32 + c]] = pval[(size_t)(r0 + w) * 32 + c];
    }
    __syncthreads();
#pragma unroll
    for (int w = 0; w < 4; w++) {
        float4* grow = reinterpret_cast<float4*>(attnF + (size_t)(r0 + w) * N_TOK);
#pragma unroll
        for (int t = 0; t < 4; t++)
            grow[t * 256 + tid] = rb4[w * 1024 + t * 256 + tid];
    }
}

// ---------------------------------------------------------------------------
// Row LayerNorm (biased var), in-place on fp32 resid. One wave per row.
// ---------------------------------------------------------------------------
__global__ __launch_bounds__(64) void ln_kernel(
    float* __restrict__ resb, const float* __restrict__ g,
    const float* __restrict__ b)
{
    const int i = blockIdx.x, lane = threadIdx.x;
    float4* rowp = reinterpret_cast<float4*>(resb + (size_t)i * DIM);
    float4 x = rowp[lane];
    float s  = x.x + x.y + x.z + x.w;
    float sq = x.x * x.x + x.y * x.y + x.z * x.z + x.w * x.w;
#pragma unroll
    for (int off = 32; off; off >>= 1) {
        s  += __shfl_xor(s, off);
        sq += __shfl_xor(sq, off);
    }
    const float mu  = s * (1.f / DIM);
    const float var = sq * (1.f / DIM) - mu * mu;
    const float rstd = rsqrtf(var + LN_EPS);
    const int col = lane * 4;
    float4 o;
    o.x = (x.x - mu) * rstd * g[col + 0] + b[col + 0];
    o.y = (x.y - mu) * rstd * g[col + 1] + b[col + 1];
    o.z = (x.z - mu) * rstd * g[col + 2] + b[col + 2];
    o.w = (x.w - mu) * rstd * g[col + 3] + b[col + 3];
    rowp[lane] = o;
}

// ---------------------------------------------------------------------------
extern "C" void kernel_launch(void* const* d_in, const int* in_sizes, int n_in,
                              void* d_out, int out_size, void* d_ws, size_t ws_size,
                              hipStream_t stream)
{
    const float* key_in   = (const float*)d_in[0];
    const float* value_in = (const float*)d_in[1];
    const float* query_in = (const float*)d_in[2];
    const float* Wq = (const float*)d_in[3];
    const float* bq = (const float*)d_in[4];
    const float* Wk = (const float*)d_in[5];
    const float* bk = (const float*)d_in[6];
    const float* Wv = (const float*)d_in[7];
    const float* bv = (const float*)d_in[8];
    const float* Wo = (const float*)d_in[9];
    const float* bo = (const float*)d_in[10];
    const float* ln_g = (const float*)d_in[11];
    const float* ln_b = (const float*)d_in[12];

    float* outF  = (float*)d_out;                     // (N, D) fp32
    float* attnF = outF + (size_t)N_TOK * DIM;        // (H, N, N) fp32

    // Large scratch carved inside the attn output region (all consumed before
    // attn_write overwrites it; attn_write runs last).
    const size_t SC = 33554432;               // 2 ushorts per attn float slot
    ushort* sb   = (ushort*)attnF;            // u16 sortable keys (128 MB)
    float*  qf   = attnF + SC;
    float*  kf   = attnF + SC + 1048576;
    float*  vf   = attnF + SC + 2097152;
    ushort* qb   = (ushort*)(attnF + SC + 3145728);
    ushort* kb   = (ushort*)(attnF + SC + 3670016);
    ushort* ctxb = (ushort*)(attnF + SC + 4194304);

    // d_ws (round 0 proved >= 22 MB usable): pval/pidx + bf16 casts (~6.3 MB)
    float*  pval    = (float*)d_ws;                     // 2 MB
    int*    pidx    = (int*)d_ws + 524288;              // 2 MB
    ushort* value_b = (ushort*)((char*)d_ws + (4u << 20));   // 2 MB
    ushort* Wv_b    = (ushort*)((char*)d_ws + (6u << 20));   // 128 KB
    ushort* Wo_b    = (ushort*)((char*)d_ws + (6u << 20) + 131072);

    cast_kernel<<<dim3((1048576 + 65536 + 65536) / 4 / 256), 256, 0, stream>>>(
        value_in, Wv, Wo, value_b, Wv_b, Wo_b);
    qk_gemm_f32<<<dim3(8, 64), 256, 0, stream>>>(
        query_in, key_in, Wq, bq, Wk, bk, qf, kf, qb, kb);
    mfma_gemm<<<dim3(4, 64), 256, 0, stream>>>(value_b, Wv_b, bv, nullptr, vf);

    scores_kernel<<<dim3(32, 32, NH), 256, 0, stream>>>(qb, kb, sb);
    select_kernel<<<dim3(N_TOK * NH / 4), 256, 0, stream>>>(
        sb, qf, kf, vf, pval, pidx, ctxb);

    mfma_gemm<<<dim3(4, 64), 256, 0, stream>>>(ctxb, Wo_b, bo, query_in, outF);
    ln_kernel<<<N_TOK, 64, 0, stream>>>(outF, ln_g, ln_b);

    attn_write<<<N_TOK * NH / 4, 256, 0, stream>>>(pval, pidx, attnF);
}